// Round 1
// baseline (526.649 us; speedup 1.0000x reference)
//
#include <hip/hip_runtime.h>

#define B_IMG 8
#define D_DIM 32
#define NPIX 262144      // 512*512
#define K_CL 16
#define CHUNK 2048
#define CHUNKS (NPIX / CHUNK)   // 128
#define PPT 8                   // pixels per thread = CHUNK/256
#define ACC_STRIDE 272          // 256 + 16: rows stay 16B-aligned, banks ~2-way

__device__ __forceinline__ float wave_sum(float v) {
#pragma unroll
  for (int off = 32; off > 0; off >>= 1) v += __shfl_xor(v, off, 64);
  return v;
}

// Reduce each of the 16 rows of acc (256 floats each) to a scalar, zero the row,
// and atomically add into target[r*stride]. 4 waves x 4 rows each.
__device__ __forceinline__ void flush_acc(float (*acc)[ACC_STRIDE], int tid,
                                          float* target, int stride) {
  const int w = tid >> 6, lane = tid & 63;
#pragma unroll
  for (int rr = 0; rr < 4; rr++) {
    const int r = (w << 2) | rr;
    float4 v = *(float4*)(&acc[r][lane << 2]);
    *(float4*)(&acc[r][lane << 2]) = make_float4(0.f, 0.f, 0.f, 0.f);
    float tot = wave_sum(v.x + v.y + v.z + v.w);
    if (lane == 0) unsafeAtomicAdd(&target[r * stride], tot);
  }
}

// ---------------- Pass A: per-cluster counts and per-(k,d) sums ----------------
__global__ __launch_bounds__(256) void k_sums(const float* __restrict__ emb,
                                              const int* __restrict__ gt,
                                              float* __restrict__ sums,
                                              float* __restrict__ counts) {
  __shared__ alignas(16) float acc[K_CL][ACC_STRIDE];
  const int tid = threadIdx.x;
  const int b = blockIdx.x >> 7;            // CHUNKS == 128
  const int chunk = blockIdx.x & (CHUNKS - 1);
  const int base = chunk * CHUNK;

  int lb[PPT];
  {
    const int4* lp = (const int4*)(gt + (size_t)b * NPIX + base);
    int4 a0 = lp[tid];
    int4 a1 = lp[256 + tid];
    lb[0] = a0.x; lb[1] = a0.y; lb[2] = a0.z; lb[3] = a0.w;
    lb[4] = a1.x; lb[5] = a1.y; lb[6] = a1.z; lb[7] = a1.w;
  }
#pragma unroll
  for (int k = 0; k < K_CL; k++) acc[k][tid] = 0.f;
  __syncthreads();

  // counts (raw, clamping happens in consumers)
#pragma unroll
  for (int j = 0; j < PPT; j++) acc[lb[j]][tid] += 1.0f;
  __syncthreads();
  flush_acc(acc, tid, counts + b * K_CL, 1);
  __syncthreads();

  for (int d = 0; d < D_DIM; d++) {
    const float4* pp = (const float4*)(emb + ((size_t)b * D_DIM + d) * NPIX + base);
    alignas(16) float v[PPT];
    *(float4*)&v[0] = pp[tid];
    *(float4*)&v[4] = pp[256 + tid];
#pragma unroll
    for (int j = 0; j < PPT; j++) acc[lb[j]][tid] += v[j];
    __syncthreads();
    flush_acc(acc, tid, sums + (size_t)b * K_CL * D_DIM + d, D_DIM);
    __syncthreads();
  }
}

// ------------- Pass C: variance (pull) loss + distance/reg per image -------------
__global__ __launch_bounds__(256) void k_var(const float* __restrict__ emb,
                                             const int* __restrict__ gt,
                                             const float* __restrict__ sums,
                                             const float* __restrict__ counts,
                                             float* __restrict__ var_sums,
                                             float* __restrict__ dist_reg) {
  __shared__ alignas(16) float acc[K_CL][ACC_STRIDE];
  __shared__ float m_lds[D_DIM * K_CL];   // [d][k] for broadcast-friendly reads
  __shared__ float msq[K_CL];
  __shared__ float red4[4];
  const int tid = threadIdx.x;
  const int b = blockIdx.x >> 7;
  const int chunk = blockIdx.x & (CHUNKS - 1);
  const int base = chunk * CHUNK;

  // rebuild means from sums/counts (tiny, L2-cached)
  for (int e = tid; e < K_CL * D_DIM; e += 256) {
    const int k = e >> 5, d = e & 31;
    const float c = fmaxf(counts[b * K_CL + k], 1.0f);
    m_lds[d * K_CL + k] = sums[((size_t)b * K_CL + k) * D_DIM + d] / c;
  }
#pragma unroll
  for (int k = 0; k < K_CL; k++) acc[k][tid] = 0.f;
  __syncthreads();
  if (tid < K_CL) {
    float s = 0.f;
#pragma unroll
    for (int d = 0; d < D_DIM; d++) { float m = m_lds[d * K_CL + tid]; s = fmaf(m, m, s); }
    msq[tid] = s;
  }
  __syncthreads();

  // one block per image computes the O(K^2 D) distance loss + reg loss
  if (chunk == 0) {
    const int i = tid >> 4, j = tid & 15;   // 256 threads = all (i,j) pairs
    float sq = 0.f;
#pragma unroll
    for (int d = 0; d < D_DIM; d++) {
      const float df = m_lds[d * K_CL + i] - m_lds[d * K_CL + j];
      sq = fmaf(df, df, sq);
    }
    float contrib = 0.f;
    if (i < j) {                            // upper triangle, k=1
      const float h = fmaxf(3.0f - sqrtf(sq), 0.0f);  // 2*DIST_THETA = 3
      contrib = h * h;
    }
    const float tot = wave_sum(contrib);
    if ((tid & 63) == 0) red4[tid >> 6] = tot;
    __syncthreads();
    if (tid == 0) {
      const float dist = (red4[0] + red4[1] + red4[2] + red4[3]) * (1.0f / 240.0f);
      float reg = 0.f;
#pragma unroll
      for (int k = 0; k < K_CL; k++) reg += sqrtf(msq[k]);
      dist_reg[b] = dist + 0.001f * (reg * (1.0f / 16.0f));   // BETA*dist + GAMMA*reg
    }
  }

  int lb[PPT];
  {
    const int4* lp = (const int4*)(gt + (size_t)b * NPIX + base);
    int4 a0 = lp[tid];
    int4 a1 = lp[256 + tid];
    lb[0] = a0.x; lb[1] = a0.y; lb[2] = a0.z; lb[3] = a0.w;
    lb[4] = a1.x; lb[5] = a1.y; lb[6] = a1.z; lb[7] = a1.w;
  }
  float a[PPT];
#pragma unroll
  for (int j = 0; j < PPT; j++) a[j] = 0.f;

  // d2 = sum_d x^2 - 2 sum_d x*m[l][d] + ||m_l||^2, accumulated in registers
  for (int d = 0; d < D_DIM; d++) {
    const float4* pp = (const float4*)(emb + ((size_t)b * D_DIM + d) * NPIX + base);
    alignas(16) float v[PPT];
    *(float4*)&v[0] = pp[tid];
    *(float4*)&v[4] = pp[256 + tid];
    const float* md = &m_lds[d * K_CL];
#pragma unroll
    for (int j = 0; j < PPT; j++) a[j] = fmaf(v[j], v[j] - 2.0f * md[lb[j]], a[j]);
  }
#pragma unroll
  for (int j = 0; j < PPT; j++) {
    const float d2 = a[j] + msq[lb[j]];
    const float dd = sqrtf(fmaxf(d2, 0.f));
    const float h = fmaxf(dd - 0.5f, 0.f);   // VAR_THETA = 0.5
    acc[lb[j]][tid] += h * h;
  }
  __syncthreads();
  flush_acc(acc, tid, var_sums + b * K_CL, 1);
}

// ---------------- Final combine: one tiny block ----------------
__global__ __launch_bounds__(128) void k_final(const float* __restrict__ counts,
                                               const float* __restrict__ var_sums,
                                               const float* __restrict__ dist_reg,
                                               float* __restrict__ out) {
  const int t = threadIdx.x;   // 128 threads: t = b*16 + k
  float pc = 0.f;
  if (t < B_IMG * K_CL) pc = var_sums[t] / fmaxf(counts[t], 1.0f);
#pragma unroll
  for (int off = 8; off > 0; off >>= 1) pc += __shfl_xor(pc, off, 64);
  __shared__ float lb[B_IMG];
  if (t < B_IMG * K_CL && (t & 15) == 0) {
    const int b = t >> 4;
    lb[b] = pc * (1.0f / 16.0f) + dist_reg[b];   // ALPHA*variance + (dist+reg)
  }
  __syncthreads();
  if (t == 0) {
    float s = 0.f;
#pragma unroll
    for (int b = 0; b < B_IMG; b++) s += lb[b];
    out[0] = s * (1.0f / B_IMG);
  }
}

extern "C" void kernel_launch(void* const* d_in, const int* in_sizes, int n_in,
                              void* d_out, int out_size, void* d_ws, size_t ws_size,
                              hipStream_t stream) {
  const float* emb = (const float*)d_in[0];
  const int* gt = (const int*)d_in[1];
  float* out = (float*)d_out;

  float* sums = (float*)d_ws;                          // B*K*D = 4096 floats
  float* counts = sums + B_IMG * K_CL * D_DIM;         // 128
  float* var_sums = counts + B_IMG * K_CL;             // 128
  float* dist_reg = var_sums + B_IMG * K_CL;           // 8

  const size_t ws_floats = B_IMG * K_CL * D_DIM + 2 * B_IMG * K_CL + B_IMG;
  hipMemsetAsync(d_ws, 0, ws_floats * sizeof(float), stream);

  k_sums<<<dim3(B_IMG * CHUNKS), dim3(256), 0, stream>>>(emb, gt, sums, counts);
  k_var<<<dim3(B_IMG * CHUNKS), dim3(256), 0, stream>>>(emb, gt, sums, counts,
                                                        var_sums, dist_reg);
  k_final<<<dim3(1), dim3(128), 0, stream>>>(counts, var_sums, dist_reg, out);
}